// Round 13
// baseline (470.231 us; speedup 1.0000x reference)
//
#include <hip/hip_runtime.h>
#include <cstdint>
#include <cmath>

// Problem constants
#define B_   4
#define L_   2048
#define H_   2048
#define NH_  16
#define HD_  128
#define ML_  (B_*L_)   // 8192 rows total

using short8 = __attribute__((ext_vector_type(8))) short;
using f32x4  = __attribute__((ext_vector_type(4))) float;
using f32x16 = __attribute__((ext_vector_type(16))) float;
using uint4v = __attribute__((ext_vector_type(4))) unsigned;

__device__ inline short f2bf(float f){
  unsigned u = __builtin_bit_cast(unsigned, f);
  unsigned r = u + 0x7FFFu + ((u >> 16) & 1u);   // RNE
  return (short)(r >> 16);
}
__device__ inline float bf2f(short s){
  unsigned u = ((unsigned)(unsigned short)s) << 16;
  return __builtin_bit_cast(float, u);
}

// async global->LDS, 16B per lane, wave-uniform LDS base + lane*16
#define GLD16(gp, lp) __builtin_amdgcn_global_load_lds(                      \
    (const __attribute__((address_space(1))) void*)(gp),                     \
    (__attribute__((address_space(3))) void*)(lp), 16, 0, 0)

// pack 2 f32 -> 2 bf16 (RNE), dst.lo16 = lo, dst.hi16 = hi
__device__ inline unsigned cvtpk_bf16(float lo, float hi){
  unsigned d;
  asm("v_cvt_pk_bf16_f32 %0, %1, %2" : "=v"(d) : "v"(lo), "v"(hi));
  return d;
}
// NOTE: only safe when a and b are provably-distinct values (round-3 NaN:
// equal-valued operands can be register-coalesced into one VGPR).
__device__ inline void permswap32(unsigned &a, unsigned &b){
  asm volatile("v_permlane32_swap_b32 %0, %1" : "+v"(a), "+v"(b));
}
__device__ inline float cross_half_max(float x){
  return fmaxf(x, __shfl_xor(x, 32));
}
__device__ inline float cross_half_add(float x){
  return x + __shfl_xor(x, 32);
}

__device__ inline void cvt8(const float* __restrict__ in, short* __restrict__ out,
                            int i){
  const float4* p = (const float4*)(in + (size_t)i * 8);
  float4 a = p[0], b = p[1];
  short8 s;
  s[0]=f2bf(a.x); s[1]=f2bf(a.y); s[2]=f2bf(a.z); s[3]=f2bf(a.w);
  s[4]=f2bf(b.x); s[5]=f2bf(b.y); s[6]=f2bf(b.z); s[7]=f2bf(b.w);
  *(short8*)(out + (size_t)i * 8) = s;
}

// ---------------------------------------------------------------------------
// RoPE cos/sin table: [2048][64] each, f32 (fallback path)
// ---------------------------------------------------------------------------
__global__ void rope_table(float* __restrict__ cosT, float* __restrict__ sinT){
  int idx = blockIdx.x * 256 + threadIdx.x;
  if (idx >= L_ * 64) return;
  int l = idx >> 6, d = idx & 63;
  float invf = powf(10000.0f, -(float)d * (1.0f/64.0f));
  float fr = (float)l * invf;
  cosT[idx] = cosf(fr);
  sinT[idx] = sinf(fr);
}

// f32 -> bf16 elementwise (fallback path)
__global__ __launch_bounds__(256)
void cvt_bf16(const float* __restrict__ in, short* __restrict__ out, int n8){
  int i = blockIdx.x * 256 + threadIdx.x;
  if (i >= n8) return;
  cvt8(in, out, i);
}

// ---------------------------------------------------------------------------
// prep: one dispatch for x->bf16, packed W(q|k|v)->bf16, Wo->bf16, rope table
//   blocks: [0,8192) x ; [8192,14336) W3 ; [14336,16384) Wo ; [16384,16896) rope
// ---------------------------------------------------------------------------
__global__ __launch_bounds__(256)
void prep(const float* __restrict__ x,  const float* __restrict__ Wq,
          const float* __restrict__ Wk, const float* __restrict__ Wv,
          const float* __restrict__ Wo, short* __restrict__ xb,
          short* __restrict__ Wb, short* __restrict__ WoB,
          float* __restrict__ cosT, float* __restrict__ sinT)
{
  const int blk = blockIdx.x, tid = threadIdx.x;
  const int per = H_ * H_ / 8;
  if (blk < 8192) {
    cvt8(x, xb, blk * 256 + tid);
  } else if (blk < 14336) {
    int i = (blk - 8192) * 256 + tid;          // 0 .. 3*per-1 (packed dest)
    const float* src; int j;
    if (i < per)          { src = Wq; j = i; }
    else if (i < 2 * per) { src = Wk; j = i - per; }
    else                  { src = Wv; j = i - 2 * per; }
    const float4* p = (const float4*)(src + (size_t)j * 8);
    float4 a = p[0], b = p[1];
    short8 s;
    s[0]=f2bf(a.x); s[1]=f2bf(a.y); s[2]=f2bf(a.z); s[3]=f2bf(a.w);
    s[4]=f2bf(b.x); s[5]=f2bf(b.y); s[6]=f2bf(b.z); s[7]=f2bf(b.w);
    *(short8*)(Wb + (size_t)i * 8) = s;
  } else if (blk < 16384) {
    cvt8(Wo, WoB, (blk - 14336) * 256 + tid);
  } else {
    int idx = (blk - 16384) * 256 + tid;       // 0 .. 131071
    int l = idx >> 6, d = idx & 63;
    float invf = powf(10000.0f, -(float)d * (1.0f/64.0f));
    float fr = (float)l * invf;
    cosT[idx] = cosf(fr);
    sinT[idx] = sinf(fr);
  }
}

// ---------------------------------------------------------------------------
// GEMM 256x256 tile, counted-vmcnt deep pipeline (R6/R8 schedule, unchanged)
// — inner loop switched 16x16x32 -> 32x32x16 MFMA this round:
//   µbench: 32x32 = 2382 TF vs 16x16 = 2075 TF ceiling (17% cheaper/FLOP),
//   halves MFMA instruction count (16 vs 32 per wave-tile). Operand mapping
//   proven in flash_attn: A lane holds row=l&31, k=hi*8+j; B lane col=l&31;
//   D: row=(r&3)+8*(r>>2)+4*hi, col=l&31 (m74/m101-verified).
//   Staging, 4-buffer vmcnt(8) schedule, swizzle, barriers: byte-identical.
// ---------------------------------------------------------------------------
template<int QKV, int OUT_F32>
__global__ __launch_bounds__(512, 2)
void gemm256_bt(const short* __restrict__ A, const short* __restrict__ Bw,
                void* __restrict__ C0, void* __restrict__ C1,
                void* __restrict__ C2)
{
  constexpr int K = 2048, N = 2048;
  __shared__ short sA[4][256 * 32];      // 64 KiB
  __shared__ short sB[4][256 * 32];      // 64 KiB
  const int tid  = threadIdx.x;
  const int lane = tid & 63;
  const int wave = tid >> 6;
  const int wr = wave >> 2, wc = wave & 3;   // 2M x 4N wave grid
  const int l31 = lane & 31, hi = lane >> 5;

  const int blk = blockIdx.x;
  int n_t, m_t;
  if constexpr (QKV) { int i = blk >> 3; n_t = (blk & 7) + 8 * (i >> 5); m_t = i & 31; }
  else               { n_t = blk & 7;    m_t = blk >> 3; }
  const int m0 = m_t * 256;
  const int nb0 = n_t * 256;             // B-row base (packed rows for QKV)

  // staging geometry: 1024 16B-slots per (matrix, tile); 2 per thread
  const int u0 = wave * 64 + lane;           // 0..511   -> rows 0..127
  const int u1 = u0 + 512;                   // 512..1023-> rows 128..255
  const int r0 = u0 >> 2, c0 = (((u0 & 3) ^ (r0 & 3) ^ ((r0 >> 2) & 3))) * 8;
  const int r1 = u1 >> 2, c1 = (((u1 & 3) ^ (r1 & 3) ^ ((r1 >> 2) & 3))) * 8;

  f32x16 acc[4][2];                      // 4 m-tiles x 2 n-tiles of 32x32
  #pragma unroll
  for (int m = 0; m < 4; m++)
    #pragma unroll
    for (int n = 0; n < 2; n++)
      #pragma unroll
      for (int r = 0; r < 16; r++) acc[m][n][r] = 0.f;

#define STAGE256(T) do {                                                     \
    const int _b = (T) & 3; const int _k = (T) * 32;                         \
    GLD16(A  + (size_t)(m0 + r0) * K + _k + c0, &sA[_b][wave * 512]);        \
    GLD16(A  + (size_t)(m0 + r1) * K + _k + c1, &sA[_b][4096 + wave * 512]); \
    GLD16(Bw + (size_t)(nb0 + r0) * K + _k + c0, &sB[_b][wave * 512]);       \
    GLD16(Bw + (size_t)(nb0 + r1) * K + _k + c1, &sB[_b][4096 + wave * 512]);\
  } while (0)

#define TILE256(T, VMN, PF) do {                                             \
    asm volatile("s_waitcnt vmcnt(" #VMN ")" ::: "memory");                  \
    __builtin_amdgcn_s_barrier();                                            \
    asm volatile("" ::: "memory");                                           \
    const short* _at = &sA[(T) & 3][0];                                      \
    const short* _bt = &sB[(T) & 3][0];                                      \
    const int _x = (l31 & 3) ^ ((l31 >> 2) & 3);                             \
    short8 af[4][2], bfr[2][2];                                              \
    _Pragma("unroll")                                                        \
    for (int kk2 = 0; kk2 < 2; kk2++) {                                      \
      const int _sl = ((kk2 * 2 + hi) ^ _x) * 8;                             \
      _Pragma("unroll")                                                      \
      for (int mt = 0; mt < 4; mt++)                                         \
        af[mt][kk2] = *(const short8*)(_at + (wr * 128 + mt * 32 + l31) * 32 + _sl); \
      _Pragma("unroll")                                                      \
      for (int nt = 0; nt < 2; nt++)                                         \
        bfr[nt][kk2] = *(const short8*)(_bt + (wc * 64 + nt * 32 + l31) * 32 + _sl); \
    }                                                                        \
    if (PF) STAGE256((T) + 3);                                               \
    __builtin_amdgcn_s_setprio(1);                                           \
    _Pragma("unroll")                                                        \
    for (int mt = 0; mt < 4; mt++)                                           \
      _Pragma("unroll")                                                      \
      for (int nt = 0; nt < 2; nt++)                                         \
        _Pragma("unroll")                                                    \
        for (int kk2 = 0; kk2 < 2; kk2++)                                    \
          acc[mt][nt] = __builtin_amdgcn_mfma_f32_32x32x16_bf16(             \
              af[mt][kk2], bfr[nt][kk2], acc[mt][nt], 0, 0, 0);              \
    __builtin_amdgcn_s_setprio(0);                                           \
  } while (0)

  // prologue: 3 tiles in flight
  STAGE256(0); STAGE256(1); STAGE256(2);

  for (int t = 0; t < 61; ++t) TILE256(t, 8, true);   // prefetch t+3 = 3..63
  TILE256(61, 8, false);
  TILE256(62, 4, false);
  TILE256(63, 0, false);

#undef STAGE256
#undef TILE256

  // epilogue: 32x32 C/D layout col=lane&31, row=(r&3)+8*(r>>2)+4*hi
  void* Cp; int cb;
  if constexpr (QKV) {
    int w = n_t >> 3;
    Cp = (w == 0) ? C0 : (w == 1) ? C1 : C2;
    cb = (n_t & 7) * 256;
  } else { Cp = C0; cb = nb0; }
  #pragma unroll
  for (int mt = 0; mt < 4; mt++)
    #pragma unroll
    for (int nt = 0; nt < 2; nt++)
      #pragma unroll
      for (int r = 0; r < 16; r++) {
        int row = m0 + wr * 128 + mt * 32 + (r & 3) + 8 * (r >> 2) + 4 * hi;
        int col = cb + wc * 64 + nt * 32 + l31;
        float v = acc[mt][nt][r];
        if constexpr (OUT_F32) ((float*)Cp)[(size_t)row * N + col] = v;
        else                   ((short*)Cp)[(size_t)row * N + col] = f2bf(v);
      }
}

// ---------------------------------------------------------------------------
// post_qkv: one dispatch for V-transpose (blocks 0..4095) and K-RoPE
// (blocks 4096..8191). Independent data -> safe to merge. Unchanged.
// ---------------------------------------------------------------------------
__global__ __launch_bounds__(256)
void post_qkv(const short* __restrict__ Vb, short* __restrict__ VT,
              short* __restrict__ Kb,
              const float* __restrict__ cosT, const float* __restrict__ sinT)
{
  __shared__ short t[64 * 64];
  const int tid = threadIdx.x;
  if (blockIdx.x < 4096) {
    const int blk = blockIdx.x;         // 64 bh x 32 ltile x 2 dtile
    const int dt = blk & 1, lt = (blk >> 1) & 31, bh = blk >> 6;
    const int b = bh >> 4, h = bh & 15;
    const int l0 = lt * 64, d0 = dt * 64;
    #pragma unroll
    for (int i = 0; i < 2; i++) {
      int u = tid + i * 256;
      int r = u >> 3, c = u & 7;
      short8 v = *(const short8*)(Vb + ((size_t)b * L_ + l0 + r) * H_ + h * HD_ + d0 + c * 8);
      *(short8*)&t[r * 64 + ((c ^ ((r >> 3) & 7)) << 3)] = v;
    }
    __syncthreads();
    #pragma unroll
    for (int i = 0; i < 2; i++) {
      int u = tid + i * 256;
      int d = u >> 3, lc = u & 7;
      short8 o;
      #pragma unroll
      for (int j = 0; j < 8; j++) {
        int l = lc * 8 + j;
        o[j] = t[l * 64 + (((d >> 3) ^ (lc & 7)) << 3) + (d & 7)];
      }
      *(short8*)(VT + ((size_t)bh * HD_ + d0 + d) * L_ + l0 + lc * 8) = o;
    }
  } else {
    int idx = (blockIdx.x - 4096) * 256 + tid;
    int row = idx >> 7;
    int rem = idx & 127;
    int h = rem >> 3, ch = rem & 7;
    int l = row & (L_ - 1);
    short* base = Kb + (size_t)row * H_ + h * HD_ + ch * 8;
    short8 lo = *(short8*)base;
    short8 hi = *(short8*)(base + 64);
    const float* cp = cosT + l * 64 + ch * 8;
    const float* sp = sinT + l * 64 + ch * 8;
    short8 nlo, nhi;
    #pragma unroll
    for (int j = 0; j < 8; j++) {
      float c = cp[j], s = sp[j];
      float x0 = bf2f(lo[j]), x1 = bf2f(hi[j]);
      nlo[j] = f2bf(x0 * c - x1 * s);
      nhi[j] = f2bf(x1 * c + x0 * s);
    }
    *(short8*)base        = nlo;
    *(short8*)(base + 64) = nhi;
  }
}

// ---------------------------------------------------------------------------
// Flash attention — PROVEN R10 8-wave/32-q structure (unchanged from R12).
// ---------------------------------------------------------------------------
__global__ __launch_bounds__(512, 2)
void flash_attn(const short* __restrict__ Qb, const short* __restrict__ Kb,
                const short* __restrict__ VT, short* __restrict__ AO,
                const float* __restrict__ cosT, const float* __restrict__ sinT)
{
  __shared__ short lds_k[2][64 * 128];    // [kv][d-chunks swz]  32 KiB
  __shared__ short lds_v[2][128 * 64];    // [d][kv-chunks swz]  32 KiB
  __shared__ float f_lds[8][32];

  const int blk = blockIdx.x;             // 512 = 64 bh x 8 q-blocks
  int bh, j;
  if (blk < 256) { bh = blk & 63; j = 7 - (blk >> 6); }        // heavy first
  else           { int u = blk - 256; bh = u & 63; j = u >> 6; } // pair sums 36
  const int q0 = j * 256;
  const int T  = 4 * j + 4;               // kv tiles for this q-block
  const int h = bh & 15, b = bh >> 4;
  const int tid = threadIdx.x, wave = tid >> 6, lane = tid & 63;
  const int hi = lane >> 5, l31 = lane & 31;
  const size_t rowbase = (size_t)b * L_;
  const int colbase = h * HD_;
  const short* Kbh  = Kb + rowbase * H_ + colbase;     // row stride H_
  const short* VTbh = VT + (size_t)bh * HD_ * L_;      // row stride L_
  const int qw = q0 + wave * 32;
  const int qabs = qw + l31;
  const int fsw = (l31 & 7) ^ ((l31 >> 3) & 3);        // read-side swizzle

  // Q fragments (B-operand) with fused RoPE + 1/sqrt(128) scale.
  short8 qf[8];
  {
    const short* qp = Qb + (rowbase + qabs) * H_ + colbase + hi * 8;
    short8 qraw[8];
    #pragma unroll
    for (int c = 0; c < 8; c++) qraw[c] = *(const short8*)(qp + c * 16);
    const int lq = qabs & (L_ - 1);
    const float* cp = cosT + lq * 64 + hi * 8;
    const float* sp = sinT + lq * 64 + hi * 8;
    #pragma unroll
    for (int c = 0; c < 4; c++) {
      #pragma unroll
      for (int jj = 0; jj < 8; jj++) {
        float cc = cp[c * 16 + jj], ss = sp[c * 16 + jj];
        float lo = bf2f(qraw[c][jj]), hv = bf2f(qraw[c + 4][jj]);
        qf[c][jj]     = f2bf((lo * cc - hv * ss) * 0.08838834764831845f);
        qf[c + 4][jj] = f2bf((hv * cc + lo * ss) * 0.08838834764831845f);
      }
    }
  }

  f32x16 acc_o[4];
  #pragma unroll
  for (int d = 0; d < 4; d++)
    #pragma unroll
    for (int r = 0; r < 16; r++) acc_o[d][r] = 0.f;
  float m_ = -__builtin_inff(), l_ = 0.f;

  // stage one KV tile into buffer bufi (all 8 waves cooperate)
  auto stage = [&](int k0s, int bufi) {
    #pragma unroll
    for (int i = 0; i < 2; i++) {
      int c = wave * 2 + i;               // 0..15, wave-uniform
      {
        int rt = c * 4 + (lane >> 4);                  // kv row in tile
        int cg = (lane & 15) ^ (rt & 7) ^ ((rt >> 3) & 3);
        const short* gp = Kbh + (size_t)(k0s + rt) * H_ + cg * 8;
        GLD16(gp, &lds_k[bufi][c * 512]);
      }
      {
        int rd = c * 8 + (lane >> 3);                  // head-dim row
        int cg = (lane & 7) ^ (rd & 7) ^ ((rd >> 3) & 3);
        const short* gp = VTbh + (size_t)rd * L_ + k0s + cg * 8;
        GLD16(gp, &lds_v[bufi][c * 512]);
      }
    }
  };

  stage(0, 0);
  __syncthreads();                        // vmcnt(0) drained: buf0 ready

  for (int t = 0; t < T; ++t) {
    const int k0 = t * 64;
    if (t + 1 < T) stage((t + 1) * 64, (t + 1) & 1);
    const short* kb_ = lds_k[t & 1];
    const short* vb_ = lds_v[t & 1];

    if (k0 <= qw + 31) {                  // wave-uniform active check
      // ---- S^T = K Q^T : 2 x (8-chain) 32x32x16 MFMA ----
      f32x16 p0, p1;
      #pragma unroll
      for (int r = 0; r < 16; r++) { p0[r] = 0.f; p1[r] = 0.f; }
      __builtin_amdgcn_s_setprio(1);
      #pragma unroll
      for (int c = 0; c < 8; c++) {
        int ch = (c * 2 + hi) ^ fsw;
        short8 kf0 = *(const short8*)(kb_ + l31 * 128 + ch * 8);
        short8 kf1 = *(const short8*)(kb_ + (32 + l31) * 128 + ch * 8);
        p0 = __builtin_amdgcn_mfma_f32_32x32x16_bf16(kf0, qf[c], p0, 0, 0, 0);
        p1 = __builtin_amdgcn_mfma_f32_32x32x16_bf16(kf1, qf[c], p1, 0, 0, 0);
      }
      __builtin_amdgcn_s_setprio(0);

      // ---- causal mask (<=2 tiles per wave hit this) ----
      if (k0 + 63 > qw) {
        #pragma unroll
        for (int r = 0; r < 16; r++) {
          int kvl = (r & 3) + 8 * (r >> 2) + 4 * hi;
          if (k0 + kvl > qabs)      p0[r] = -__builtin_inff();
          if (k0 + 32 + kvl > qabs) p1[r] = -__builtin_inff();
        }
      }

      // ---- online softmax, in-register, with defer-max (T13) ----
      float mt = p0[0];
      #pragma unroll
      for (int r = 1; r < 16; r++) mt = fmaxf(mt, p0[r]);
      #pragma unroll
      for (int r = 0; r < 16; r++) mt = fmaxf(mt, p1[r]);
      mt = cross_half_max(mt);
      if (!__all(mt <= m_ + 8.0f)) {
        float mnew = fmaxf(m_, mt);
        float f = __expf(m_ - mnew);
        m_ = mnew;
        l_ *= f;
        if (lane < 32) f_lds[wave][lane] = f;
        f32x4 fr[4];
        #pragma unroll
        for (int i = 0; i < 4; i++)
          fr[i] = *(const f32x4*)&f_lds[wave][i * 8 + hi * 4];
        #pragma unroll
        for (int d = 0; d < 4; d++)
          #pragma unroll
          for (int r = 0; r < 16; r++) acc_o[d][r] *= fr[r >> 2][r & 3];
      }
      float ls = 0.f;
      #pragma unroll
      for (int r = 0; r < 16; r++) { p0[r] = __expf(p0[r] - m_); ls += p0[r]; }
      #pragma unroll
      for (int r = 0; r < 16; r++) { p1[r] = __expf(p1[r] - m_); ls += p1[r]; }
      ls = cross_half_add(ls);
      l_ += ls;

      // ---- O += P V : build A-frags (cvt_pk + permlane32_swap), 16 MFMA ----
      __builtin_amdgcn_s_setprio(1);
      #pragma unroll
      for (int ks = 0; ks < 4; ks++) {
        const f32x16 &pp = (ks < 2) ? p0 : p1;
        const int kk = (ks & 1) * 8;
        unsigned a0 = cvtpk_bf16(pp[kk + 0], pp[kk + 1]);
        unsigned b0 = cvtpk_bf16(pp[kk + 4], pp[kk + 5]);
        permswap32(a0, b0);               // a0 = word0, b0 = word2
        unsigned a1 = cvtpk_bf16(pp[kk + 2], pp[kk + 3]);
        unsigned b1 = cvtpk_bf16(pp[kk + 6], pp[kk + 7]);
        permswap32(a1, b1);               // a1 = word1, b1 = word3
        uint4v w; w[0] = a0; w[1] = a1; w[2] = b0; w[3] = b1;
        short8 af = __builtin_bit_cast(short8, w);
        #pragma unroll
        for (int db = 0; db < 4; db++) {
          int d  = db * 32 + l31;
          int ch = (ks * 2 + hi) ^ fsw;
          short8 vf = *(const short8*)(vb_ + d * 64 + ch * 8);
          acc_o[db] = __builtin_amdgcn_mfma_f32_32x32x16_bf16(af, vf, acc_o[db], 0, 0, 0);
        }
      }
      __builtin_amdgcn_s_setprio(0);
    }
    __syncthreads();   // readers done with buf[t&1]; stage(t+1) landed
  }

  // ---- normalize and write O ----
  if (lane < 32) f_lds[wave][lane] = 1.0f / l_;
  f32x4 lr[4];
  #pragma unroll
  for (int i = 0; i < 4; i++)
    lr[i] = *(const f32x4*)&f_lds[wave][i * 8 + hi * 4];
  #pragma unroll
  for (int db = 0; db < 4; db++)
    #pragma unroll
    for (int r = 0; r < 16; r++) {
      int row = qw + (r & 3) + 8 * (r >> 2) + 4 * hi;
      AO[(rowbase + row) * H_ + colbase + db * 32 + l31] =
          f2bf(acc_o[db][r] * lr[r >> 2][r & 3]);
    }
}

// ---------------------------------------------------------------------------
extern "C" void kernel_launch(void* const* d_in, const int* in_sizes, int n_in,
                              void* d_out, int out_size, void* d_ws, size_t ws_size,
                              hipStream_t stream)
{
  const float* x  = (const float*)d_in[0];
  // d_in[1] = mask (tril causal) — implemented analytically
  const float* Wq = (const float*)d_in[2];
  const float* Wk = (const float*)d_in[3];
  const float* Wv = (const float*)d_in[4];
  const float* Wo = (const float*)d_in[5];
  float* out = (float*)d_out;

  char* ws = (char*)d_ws;
  const size_t SZ = (size_t)ML_ * H_ * sizeof(short);  // 32 MiB
  short* Qb = (short*)(ws);
  short* Kb = (short*)(ws + SZ);
  short* Vb = (short*)(ws + 2 * SZ);
  short* xb = (short*)(ws + 3 * SZ);   // x bf16; dead after QKV GEMM
  short* VT = xb;                      // V^T [bh][d][l], reuses xb region
  short* AO = Vb;                      // attn out, reuses Vb (dead after transpose)
  float* cosT = (float*)(ws + 4 * SZ);
  float* sinT = cosT + (size_t)L_ * 64;
  short* Wb  = (short*)(ws + 4 * SZ + (size_t)(1 << 20));  // 24 MiB packed QKV
  short* WoB = Wb + (size_t)3 * H_ * H_;                   // 8 MiB
  const size_t NEED_FUSED = 4 * SZ + (1 << 20) + (size_t)4 * H_ * H_ * sizeof(short);
  const bool fused = ws_size >= NEED_FUSED;

  if (fused) {
    prep<<<16896, 256, 0, stream>>>(x, Wq, Wk, Wv, Wo, xb, Wb, WoB, cosT, sinT);
    gemm256_bt<1, 0><<<768, 512, 0, stream>>>(xb, Wb, Qb, Kb, Vb);
    post_qkv<<<8192, 256, 0, stream>>>(Vb, VT, Kb, cosT, sinT);
    flash_attn<<<512, 512, 0, stream>>>(Qb, Kb, VT, AO, cosT, sinT);
    gemm256_bt<0, 1><<<256, 512, 0, stream>>>(AO, WoB, out, out, out);
  } else {
    rope_table<<<512, 256, 0, stream>>>(cosT, sinT);
    cvt_bf16<<<ML_ * H_ / 8 / 256, 256, 0, stream>>>(x, xb, ML_ * H_ / 8);
    cvt_bf16<<<H_ * H_ / 8 / 256, 256, 0, stream>>>(Wq, Wb, H_ * H_ / 8);
    gemm256_bt<0, 0><<<256, 512, 0, stream>>>(xb, Wb, Qb, Qb, Qb);
    cvt_bf16<<<H_ * H_ / 8 / 256, 256, 0, stream>>>(Wk, Wb, H_ * H_ / 8);
    gemm256_bt<0, 0><<<256, 512, 0, stream>>>(xb, Wb, Kb, Kb, Kb);
    cvt_bf16<<<H_ * H_ / 8 / 256, 256, 0, stream>>>(Wv, Wb, H_ * H_ / 8);
    gemm256_bt<0, 0><<<256, 512, 0, stream>>>(xb, Wb, Vb, Vb, Vb);
    post_qkv<<<8192, 256, 0, stream>>>(Vb, VT, Kb, cosT, sinT);
    flash_attn<<<512, 512, 0, stream>>>(Qb, Kb, VT, AO, cosT, sinT);
    cvt_bf16<<<H_ * H_ / 8 / 256, 256, 0, stream>>>(Wo, Wb, H_ * H_ / 8);
    gemm256_bt<0, 1><<<256, 512, 0, stream>>>(AO, Wb, out, out, out);
  }
}

// Round 14
// 436.375 us; speedup vs baseline: 1.0776x; 1.0776x over previous
//
#include <hip/hip_runtime.h>
#include <cstdint>
#include <cmath>

// Problem constants
#define B_   4
#define L_   2048
#define H_   2048
#define NH_  16
#define HD_  128
#define ML_  (B_*L_)   // 8192 rows total

using short8 = __attribute__((ext_vector_type(8))) short;
using f32x4  = __attribute__((ext_vector_type(4))) float;
using f32x16 = __attribute__((ext_vector_type(16))) float;
using uint4v = __attribute__((ext_vector_type(4))) unsigned;

__device__ inline short f2bf(float f){
  unsigned u = __builtin_bit_cast(unsigned, f);
  unsigned r = u + 0x7FFFu + ((u >> 16) & 1u);   // RNE
  return (short)(r >> 16);
}
__device__ inline float bf2f(short s){
  unsigned u = ((unsigned)(unsigned short)s) << 16;
  return __builtin_bit_cast(float, u);
}

// async global->LDS, 16B per lane, wave-uniform LDS base + lane*16
#define GLD16(gp, lp) __builtin_amdgcn_global_load_lds(                      \
    (const __attribute__((address_space(1))) void*)(gp),                     \
    (__attribute__((address_space(3))) void*)(lp), 16, 0, 0)

// pack 2 f32 -> 2 bf16 (RNE), dst.lo16 = lo, dst.hi16 = hi
__device__ inline unsigned cvtpk_bf16(float lo, float hi){
  unsigned d;
  asm("v_cvt_pk_bf16_f32 %0, %1, %2" : "=v"(d) : "v"(lo), "v"(hi));
  return d;
}
// NOTE: only safe when a and b are provably-distinct values (round-3 NaN:
// equal-valued operands can be register-coalesced into one VGPR).
__device__ inline void permswap32(unsigned &a, unsigned &b){
  asm volatile("v_permlane32_swap_b32 %0, %1" : "+v"(a), "+v"(b));
}
__device__ inline float cross_half_max(float x){
  return fmaxf(x, __shfl_xor(x, 32));
}
__device__ inline float cross_half_add(float x){
  return x + __shfl_xor(x, 32);
}

__device__ inline void cvt8(const float* __restrict__ in, short* __restrict__ out,
                            int i){
  const float4* p = (const float4*)(in + (size_t)i * 8);
  float4 a = p[0], b = p[1];
  short8 s;
  s[0]=f2bf(a.x); s[1]=f2bf(a.y); s[2]=f2bf(a.z); s[3]=f2bf(a.w);
  s[4]=f2bf(b.x); s[5]=f2bf(b.y); s[6]=f2bf(b.z); s[7]=f2bf(b.w);
  *(short8*)(out + (size_t)i * 8) = s;
}

// ---------------------------------------------------------------------------
// RoPE cos/sin table: [2048][64] each, f32 (fallback path)
// ---------------------------------------------------------------------------
__global__ void rope_table(float* __restrict__ cosT, float* __restrict__ sinT){
  int idx = blockIdx.x * 256 + threadIdx.x;
  if (idx >= L_ * 64) return;
  int l = idx >> 6, d = idx & 63;
  float invf = powf(10000.0f, -(float)d * (1.0f/64.0f));
  float fr = (float)l * invf;
  cosT[idx] = cosf(fr);
  sinT[idx] = sinf(fr);
}

// f32 -> bf16 elementwise (fallback path)
__global__ __launch_bounds__(256)
void cvt_bf16(const float* __restrict__ in, short* __restrict__ out, int n8){
  int i = blockIdx.x * 256 + threadIdx.x;
  if (i >= n8) return;
  cvt8(in, out, i);
}

// ---------------------------------------------------------------------------
// prep: one dispatch for x->bf16, packed W(q|k|v)->bf16, Wo->bf16, rope table
//   blocks: [0,8192) x ; [8192,14336) W3 ; [14336,16384) Wo ; [16384,16896) rope
// ---------------------------------------------------------------------------
__global__ __launch_bounds__(256)
void prep(const float* __restrict__ x,  const float* __restrict__ Wq,
          const float* __restrict__ Wk, const float* __restrict__ Wv,
          const float* __restrict__ Wo, short* __restrict__ xb,
          short* __restrict__ Wb, short* __restrict__ WoB,
          float* __restrict__ cosT, float* __restrict__ sinT)
{
  const int blk = blockIdx.x, tid = threadIdx.x;
  const int per = H_ * H_ / 8;
  if (blk < 8192) {
    cvt8(x, xb, blk * 256 + tid);
  } else if (blk < 14336) {
    int i = (blk - 8192) * 256 + tid;          // 0 .. 3*per-1 (packed dest)
    const float* src; int j;
    if (i < per)          { src = Wq; j = i; }
    else if (i < 2 * per) { src = Wk; j = i - per; }
    else                  { src = Wv; j = i - 2 * per; }
    const float4* p = (const float4*)(src + (size_t)j * 8);
    float4 a = p[0], b = p[1];
    short8 s;
    s[0]=f2bf(a.x); s[1]=f2bf(a.y); s[2]=f2bf(a.z); s[3]=f2bf(a.w);
    s[4]=f2bf(b.x); s[5]=f2bf(b.y); s[6]=f2bf(b.z); s[7]=f2bf(b.w);
    *(short8*)(Wb + (size_t)i * 8) = s;
  } else if (blk < 16384) {
    cvt8(Wo, WoB, (blk - 14336) * 256 + tid);
  } else {
    int idx = (blk - 16384) * 256 + tid;       // 0 .. 131071
    int l = idx >> 6, d = idx & 63;
    float invf = powf(10000.0f, -(float)d * (1.0f/64.0f));
    float fr = (float)l * invf;
    cosT[idx] = cosf(fr);
    sinT[idx] = sinf(fr);
  }
}

// ---------------------------------------------------------------------------
// GEMM 256x256 tile, counted-vmcnt deep pipeline — proven R6/R8/R10 structure
// (991 TF measured). Final structure ranking (all measured):
//   256² deep-pipe 16x16 (991 TF) > coarse 8-phase (893) > 128² 2-blk (760)
//   ≈> 256² 32x32 (960, R13: conflicts 0 but schedule-bound — informative
//   null: the binding constraint is the barrier-locked schedule, not MFMA
//   rate or LDS conflicts).
//   BK=32, 4 LDS buffers (128 KiB), 8 waves (2M x 4N), per-wave out 128x64.
//   Per tile t: vmcnt(8) -> s_barrier -> 12 ds_read_b128 -> stage(t+3) ->
//   32 MFMA (setprio). ONE barrier/tile; race-free (stage(t+3) overwrites
//   buf[(t-1)&3] whose readers retired before tile t's barrier).
// ---------------------------------------------------------------------------
template<int QKV, int OUT_F32>
__global__ __launch_bounds__(512, 2)
void gemm256_bt(const short* __restrict__ A, const short* __restrict__ Bw,
                void* __restrict__ C0, void* __restrict__ C1,
                void* __restrict__ C2)
{
  constexpr int K = 2048, N = 2048;
  __shared__ short sA[4][256 * 32];      // 64 KiB
  __shared__ short sB[4][256 * 32];      // 64 KiB
  const int tid  = threadIdx.x;
  const int lane = tid & 63;
  const int wave = tid >> 6;
  const int wr = wave >> 2, wc = wave & 3;   // 2M x 4N wave grid
  const int ln = lane & 15, g = lane >> 4;

  const int blk = blockIdx.x;
  int n_t, m_t;
  if constexpr (QKV) { int i = blk >> 3; n_t = (blk & 7) + 8 * (i >> 5); m_t = i & 31; }
  else               { n_t = blk & 7;    m_t = blk >> 3; }
  const int m0 = m_t * 256;
  const int nb0 = n_t * 256;             // B-row base (packed rows for QKV)

  // staging geometry: 1024 16B-slots per (matrix, tile); 2 per thread
  const int u0 = wave * 64 + lane;           // 0..511   -> rows 0..127
  const int u1 = u0 + 512;                   // 512..1023-> rows 128..255
  const int r0 = u0 >> 2, c0 = (((u0 & 3) ^ (r0 & 3) ^ ((r0 >> 2) & 3))) * 8;
  const int r1 = u1 >> 2, c1 = (((u1 & 3) ^ (r1 & 3) ^ ((r1 >> 2) & 3))) * 8;

  f32x4 acc[8][4];
  #pragma unroll
  for (int m = 0; m < 8; m++)
    #pragma unroll
    for (int n = 0; n < 4; n++) acc[m][n] = {0.f, 0.f, 0.f, 0.f};

#define STAGE256(T) do {                                                     \
    const int _b = (T) & 3; const int _k = (T) * 32;                         \
    GLD16(A  + (size_t)(m0 + r0) * K + _k + c0, &sA[_b][wave * 512]);        \
    GLD16(A  + (size_t)(m0 + r1) * K + _k + c1, &sA[_b][4096 + wave * 512]); \
    GLD16(Bw + (size_t)(nb0 + r0) * K + _k + c0, &sB[_b][wave * 512]);       \
    GLD16(Bw + (size_t)(nb0 + r1) * K + _k + c1, &sB[_b][4096 + wave * 512]);\
  } while (0)

#define TILE256(T, VMN, PF) do {                                             \
    asm volatile("s_waitcnt vmcnt(" #VMN ")" ::: "memory");                  \
    __builtin_amdgcn_s_barrier();                                            \
    asm volatile("" ::: "memory");                                           \
    const short* _at = &sA[(T) & 3][0];                                      \
    const short* _bt = &sB[(T) & 3][0];                                      \
    short8 af[8], bfr[4];                                                    \
    const int _sl = (g ^ (ln & 3) ^ ((ln >> 2) & 3)) * 8;                    \
    _Pragma("unroll")                                                        \
    for (int m = 0; m < 8; m++)                                              \
      af[m] = *(const short8*)(_at + (wr * 128 + m * 16 + ln) * 32 + _sl);   \
    _Pragma("unroll")                                                        \
    for (int n = 0; n < 4; n++)                                              \
      bfr[n] = *(const short8*)(_bt + (wc * 64 + n * 16 + ln) * 32 + _sl);   \
    if (PF) STAGE256((T) + 3);                                               \
    __builtin_amdgcn_s_setprio(1);                                           \
    _Pragma("unroll")                                                        \
    for (int m = 0; m < 8; m++)                                              \
      _Pragma("unroll")                                                      \
      for (int n = 0; n < 4; n++)                                            \
        acc[m][n] = __builtin_amdgcn_mfma_f32_16x16x32_bf16(af[m], bfr[n],   \
                                                            acc[m][n], 0, 0, 0); \
    __builtin_amdgcn_s_setprio(0);                                           \
  } while (0)

  // prologue: 3 tiles in flight
  STAGE256(0); STAGE256(1); STAGE256(2);

  for (int t = 0; t < 61; ++t) TILE256(t, 8, true);   // prefetch t+3 = 3..63
  TILE256(61, 8, false);
  TILE256(62, 4, false);
  TILE256(63, 0, false);

#undef STAGE256
#undef TILE256

  // epilogue: C/D layout col=lane&15, row=(lane>>4)*4+reg
  void* Cp; int cb;
  if constexpr (QKV) {
    int w = n_t >> 3;
    Cp = (w == 0) ? C0 : (w == 1) ? C1 : C2;
    cb = (n_t & 7) * 256;
  } else { Cp = C0; cb = nb0; }
  #pragma unroll
  for (int m = 0; m < 8; m++)
    #pragma unroll
    for (int n = 0; n < 4; n++)
      #pragma unroll
      for (int r = 0; r < 4; r++) {
        int row = m0 + wr * 128 + m * 16 + g * 4 + r;
        int col = cb + wc * 64 + n * 16 + ln;
        float v = acc[m][n][r];
        if constexpr (OUT_F32) ((float*)Cp)[(size_t)row * N + col] = v;
        else                   ((short*)Cp)[(size_t)row * N + col] = f2bf(v);
      }
}

// ---------------------------------------------------------------------------
// post_qkv: one dispatch for V-transpose (blocks 0..4095) and K-RoPE
// (blocks 4096..8191). Independent data -> safe to merge.
// ---------------------------------------------------------------------------
__global__ __launch_bounds__(256)
void post_qkv(const short* __restrict__ Vb, short* __restrict__ VT,
              short* __restrict__ Kb,
              const float* __restrict__ cosT, const float* __restrict__ sinT)
{
  __shared__ short t[64 * 64];
  const int tid = threadIdx.x;
  if (blockIdx.x < 4096) {
    const int blk = blockIdx.x;         // 64 bh x 32 ltile x 2 dtile
    const int dt = blk & 1, lt = (blk >> 1) & 31, bh = blk >> 6;
    const int b = bh >> 4, h = bh & 15;
    const int l0 = lt * 64, d0 = dt * 64;
    #pragma unroll
    for (int i = 0; i < 2; i++) {
      int u = tid + i * 256;
      int r = u >> 3, c = u & 7;
      short8 v = *(const short8*)(Vb + ((size_t)b * L_ + l0 + r) * H_ + h * HD_ + d0 + c * 8);
      *(short8*)&t[r * 64 + ((c ^ ((r >> 3) & 7)) << 3)] = v;
    }
    __syncthreads();
    #pragma unroll
    for (int i = 0; i < 2; i++) {
      int u = tid + i * 256;
      int d = u >> 3, lc = u & 7;
      short8 o;
      #pragma unroll
      for (int j = 0; j < 8; j++) {
        int l = lc * 8 + j;
        o[j] = t[l * 64 + (((d >> 3) ^ (lc & 7)) << 3) + (d & 7)];
      }
      *(short8*)(VT + ((size_t)bh * HD_ + d0 + d) * L_ + l0 + lc * 8) = o;
    }
  } else {
    int idx = (blockIdx.x - 4096) * 256 + tid;
    int row = idx >> 7;
    int rem = idx & 127;
    int h = rem >> 3, ch = rem & 7;
    int l = row & (L_ - 1);
    short* base = Kb + (size_t)row * H_ + h * HD_ + ch * 8;
    short8 lo = *(short8*)base;
    short8 hi = *(short8*)(base + 64);
    const float* cp = cosT + l * 64 + ch * 8;
    const float* sp = sinT + l * 64 + ch * 8;
    short8 nlo, nhi;
    #pragma unroll
    for (int j = 0; j < 8; j++) {
      float c = cp[j], s = sp[j];
      float x0 = bf2f(lo[j]), x1 = bf2f(hi[j]);
      nlo[j] = f2bf(x0 * c - x1 * s);
      nhi[j] = f2bf(x1 * c + x0 * s);
    }
    *(short8*)base        = nlo;
    *(short8*)(base + 64) = nhi;
  }
}

// ---------------------------------------------------------------------------
// Flash attention — PROVEN R10 8-wave/32-q structure (110 µs, VGPR 100,
// 4 waves/SIMD; session-best config). Structural alternatives measured and
// rejected: 64-q/wave read-sharing (VGPR 256 -> occupancy collapse, 285 µs),
// R12 pair remap (+11 µs).
//  - Q-RoPE fused into the Q-fragment load (bit-identical math).
//  - LDS swizzle f(r) = (r&7) ^ ((r>>3)&3) on source + read (rule #21).
//  - T13 defer-max (THR=8).
// ---------------------------------------------------------------------------
__global__ __launch_bounds__(512, 2)
void flash_attn(const short* __restrict__ Qb, const short* __restrict__ Kb,
                const short* __restrict__ VT, short* __restrict__ AO,
                const float* __restrict__ cosT, const float* __restrict__ sinT)
{
  __shared__ short lds_k[2][64 * 128];    // [kv][d-chunks swz]  32 KiB
  __shared__ short lds_v[2][128 * 64];    // [d][kv-chunks swz]  32 KiB
  __shared__ float f_lds[8][32];

  const int blk = blockIdx.x;             // 512 = 64 bh x 8 q-blocks
  int bh, j;
  if (blk < 256) { bh = blk & 63; j = 7 - (blk >> 6); }        // heavy first
  else           { int u = blk - 256; bh = u & 63; j = 3 - (u >> 6); } // light last
  const int q0 = j * 256;
  const int T  = 4 * j + 4;               // kv tiles for this q-block
  const int h = bh & 15, b = bh >> 4;
  const int tid = threadIdx.x, wave = tid >> 6, lane = tid & 63;
  const int hi = lane >> 5, l31 = lane & 31;
  const size_t rowbase = (size_t)b * L_;
  const int colbase = h * HD_;
  const short* Kbh  = Kb + rowbase * H_ + colbase;     // row stride H_
  const short* VTbh = VT + (size_t)bh * HD_ * L_;      // row stride L_
  const int qw = q0 + wave * 32;
  const int qabs = qw + l31;
  const int fsw = (l31 & 7) ^ ((l31 >> 3) & 3);        // read-side swizzle

  // Q fragments (B-operand) with fused RoPE + 1/sqrt(128) scale.
  short8 qf[8];
  {
    const short* qp = Qb + (rowbase + qabs) * H_ + colbase + hi * 8;
    short8 qraw[8];
    #pragma unroll
    for (int c = 0; c < 8; c++) qraw[c] = *(const short8*)(qp + c * 16);
    const int lq = qabs & (L_ - 1);
    const float* cp = cosT + lq * 64 + hi * 8;
    const float* sp = sinT + lq * 64 + hi * 8;
    #pragma unroll
    for (int c = 0; c < 4; c++) {
      #pragma unroll
      for (int jj = 0; jj < 8; jj++) {
        float cc = cp[c * 16 + jj], ss = sp[c * 16 + jj];
        float lo = bf2f(qraw[c][jj]), hv = bf2f(qraw[c + 4][jj]);
        qf[c][jj]     = f2bf((lo * cc - hv * ss) * 0.08838834764831845f);
        qf[c + 4][jj] = f2bf((hv * cc + lo * ss) * 0.08838834764831845f);
      }
    }
  }

  f32x16 acc_o[4];
  #pragma unroll
  for (int d = 0; d < 4; d++)
    #pragma unroll
    for (int r = 0; r < 16; r++) acc_o[d][r] = 0.f;
  float m_ = -__builtin_inff(), l_ = 0.f;

  // stage one KV tile into buffer bufi (all 8 waves cooperate)
  auto stage = [&](int k0s, int bufi) {
    #pragma unroll
    for (int i = 0; i < 2; i++) {
      int c = wave * 2 + i;               // 0..15, wave-uniform
      {
        int rt = c * 4 + (lane >> 4);                  // kv row in tile
        int cg = (lane & 15) ^ (rt & 7) ^ ((rt >> 3) & 3);
        const short* gp = Kbh + (size_t)(k0s + rt) * H_ + cg * 8;
        GLD16(gp, &lds_k[bufi][c * 512]);
      }
      {
        int rd = c * 8 + (lane >> 3);                  // head-dim row
        int cg = (lane & 7) ^ (rd & 7) ^ ((rd >> 3) & 3);
        const short* gp = VTbh + (size_t)rd * L_ + k0s + cg * 8;
        GLD16(gp, &lds_v[bufi][c * 512]);
      }
    }
  };

  stage(0, 0);
  __syncthreads();                        // vmcnt(0) drained: buf0 ready

  for (int t = 0; t < T; ++t) {
    const int k0 = t * 64;
    if (t + 1 < T) stage((t + 1) * 64, (t + 1) & 1);
    const short* kb_ = lds_k[t & 1];
    const short* vb_ = lds_v[t & 1];

    if (k0 <= qw + 31) {                  // wave-uniform active check
      // ---- S^T = K Q^T : 2 x (8-chain) 32x32x16 MFMA ----
      f32x16 p0, p1;
      #pragma unroll
      for (int r = 0; r < 16; r++) { p0[r] = 0.f; p1[r] = 0.f; }
      __builtin_amdgcn_s_setprio(1);
      #pragma unroll
      for (int c = 0; c < 8; c++) {
        int ch = (c * 2 + hi) ^ fsw;
        short8 kf0 = *(const short8*)(kb_ + l31 * 128 + ch * 8);
        short8 kf1 = *(const short8*)(kb_ + (32 + l31) * 128 + ch * 8);
        p0 = __builtin_amdgcn_mfma_f32_32x32x16_bf16(kf0, qf[c], p0, 0, 0, 0);
        p1 = __builtin_amdgcn_mfma_f32_32x32x16_bf16(kf1, qf[c], p1, 0, 0, 0);
      }
      __builtin_amdgcn_s_setprio(0);

      // ---- causal mask (<=2 tiles per wave hit this) ----
      if (k0 + 63 > qw) {
        #pragma unroll
        for (int r = 0; r < 16; r++) {
          int kvl = (r & 3) + 8 * (r >> 2) + 4 * hi;
          if (k0 + kvl > qabs)      p0[r] = -__builtin_inff();
          if (k0 + 32 + kvl > qabs) p1[r] = -__builtin_inff();
        }
      }

      // ---- online softmax, in-register, with defer-max (T13) ----
      float mt = p0[0];
      #pragma unroll
      for (int r = 1; r < 16; r++) mt = fmaxf(mt, p0[r]);
      #pragma unroll
      for (int r = 0; r < 16; r++) mt = fmaxf(mt, p1[r]);
      mt = cross_half_max(mt);
      if (!__all(mt <= m_ + 8.0f)) {
        float mnew = fmaxf(m_, mt);
        float f = __expf(m_ - mnew);
        m_ = mnew;
        l_ *= f;
        if (lane < 32) f_lds[wave][lane] = f;
        f32x4 fr[4];
        #pragma unroll
        for (int i = 0; i < 4; i++)
          fr[i] = *(const f32x4*)&f_lds[wave][i * 8 + hi * 4];
        #pragma unroll
        for (int d = 0; d < 4; d++)
          #pragma unroll
          for (int r = 0; r < 16; r++) acc_o[d][r] *= fr[r >> 2][r & 3];
      }
      float ls = 0.f;
      #pragma unroll
      for (int r = 0; r < 16; r++) { p0[r] = __expf(p0[r] - m_); ls += p0[r]; }
      #pragma unroll
      for (int r = 0; r < 16; r++) { p1[r] = __expf(p1[r] - m_); ls += p1[r]; }
      ls = cross_half_add(ls);
      l_ += ls;

      // ---- O += P V : build A-frags (cvt_pk + permlane32_swap), 16 MFMA ----
      __builtin_amdgcn_s_setprio(1);
      #pragma unroll
      for (int ks = 0; ks < 4; ks++) {
        const f32x16 &pp = (ks < 2) ? p0 : p1;
        const int kk = (ks & 1) * 8;
        unsigned a0 = cvtpk_bf16(pp[kk + 0], pp[kk + 1]);
        unsigned b0 = cvtpk_bf16(pp[kk + 4], pp[kk + 5]);
        permswap32(a0, b0);               // a0 = word0, b0 = word2
        unsigned a1 = cvtpk_bf16(pp[kk + 2], pp[kk + 3]);
        unsigned b1 = cvtpk_bf16(pp[kk + 6], pp[kk + 7]);
        permswap32(a1, b1);               // a1 = word1, b1 = word3
        uint4v w; w[0] = a0; w[1] = a1; w[2] = b0; w[3] = b1;
        short8 af = __builtin_bit_cast(short8, w);
        #pragma unroll
        for (int db = 0; db < 4; db++) {
          int d  = db * 32 + l31;
          int ch = (ks * 2 + hi) ^ fsw;
          short8 vf = *(const short8*)(vb_ + d * 64 + ch * 8);
          acc_o[db] = __builtin_amdgcn_mfma_f32_32x32x16_bf16(af, vf, acc_o[db], 0, 0, 0);
        }
      }
      __builtin_amdgcn_s_setprio(0);
    }
    __syncthreads();   // readers done with buf[t&1]; stage(t+1) landed
  }

  // ---- normalize and write O ----
  if (lane < 32) f_lds[wave][lane] = 1.0f / l_;
  f32x4 lr[4];
  #pragma unroll
  for (int i = 0; i < 4; i++)
    lr[i] = *(const f32x4*)&f_lds[wave][i * 8 + hi * 4];
  #pragma unroll
  for (int db = 0; db < 4; db++)
    #pragma unroll
    for (int r = 0; r < 16; r++) {
      int row = qw + (r & 3) + 8 * (r >> 2) + 4 * hi;
      AO[(rowbase + row) * H_ + colbase + db * 32 + l31] =
          f2bf(acc_o[db][r] * lr[r >> 2][r & 3]);
    }
}

// ---------------------------------------------------------------------------
extern "C" void kernel_launch(void* const* d_in, const int* in_sizes, int n_in,
                              void* d_out, int out_size, void* d_ws, size_t ws_size,
                              hipStream_t stream)
{
  const float* x  = (const float*)d_in[0];
  // d_in[1] = mask (tril causal) — implemented analytically
  const float* Wq = (const float*)d_in[2];
  const float* Wk = (const float*)d_in[3];
  const float* Wv = (const float*)d_in[4];
  const float* Wo = (const float*)d_in[5];
  float* out = (float*)d_out;

  char* ws = (char*)d_ws;
  const size_t SZ = (size_t)ML_ * H_ * sizeof(short);  // 32 MiB
  short* Qb = (short*)(ws);
  short* Kb = (short*)(ws + SZ);
  short* Vb = (short*)(ws + 2 * SZ);
  short* xb = (short*)(ws + 3 * SZ);   // x bf16; dead after QKV GEMM
  short* VT = xb;                      // V^T [bh][d][l], reuses xb region
  short* AO = Vb;                      // attn out, reuses Vb (dead after transpose)
  float* cosT = (float*)(ws + 4 * SZ);
  float* sinT = cosT + (size_t)L_ * 64;
  short* Wb  = (short*)(ws + 4 * SZ + (size_t)(1 << 20));  // 24 MiB packed QKV
  short* WoB = Wb + (size_t)3 * H_ * H_;                   // 8 MiB
  const size_t NEED_FUSED = 4 * SZ + (1 << 20) + (size_t)4 * H_ * H_ * sizeof(short);
  const bool fused = ws_size >= NEED_FUSED;

  if (fused) {
    prep<<<16896, 256, 0, stream>>>(x, Wq, Wk, Wv, Wo, xb, Wb, WoB, cosT, sinT);
    gemm256_bt<1, 0><<<768, 512, 0, stream>>>(xb, Wb, Qb, Kb, Vb);
    post_qkv<<<8192, 256, 0, stream>>>(Vb, VT, Kb, cosT, sinT);
    flash_attn<<<512, 512, 0, stream>>>(Qb, Kb, VT, AO, cosT, sinT);
    gemm256_bt<0, 1><<<256, 512, 0, stream>>>(AO, WoB, out, out, out);
  } else {
    rope_table<<<512, 256, 0, stream>>>(cosT, sinT);
    cvt_bf16<<<ML_ * H_ / 8 / 256, 256, 0, stream>>>(x, xb, ML_ * H_ / 8);
    cvt_bf16<<<H_ * H_ / 8 / 256, 256, 0, stream>>>(Wq, Wb, H_ * H_ / 8);
    gemm256_bt<0, 0><<<256, 512, 0, stream>>>(xb, Wb, Qb, Qb, Qb);
    cvt_bf16<<<H_ * H_ / 8 / 256, 256, 0, stream>>>(Wk, Wb, H_ * H_ / 8);
    gemm256_bt<0, 0><<<256, 512, 0, stream>>>(xb, Wb, Kb, Kb, Kb);
    cvt_bf16<<<H_ * H_ / 8 / 256, 256, 0, stream>>>(Wv, Wb, H_ * H_ / 8);
    gemm256_bt<0, 0><<<256, 512, 0, stream>>>(xb, Wb, Vb, Vb, Vb);
    post_qkv<<<8192, 256, 0, stream>>>(Vb, VT, Kb, cosT, sinT);
    flash_attn<<<512, 512, 0, stream>>>(Qb, Kb, VT, AO, cosT, sinT);
    cvt_bf16<<<H_ * H_ / 8 / 256, 256, 0, stream>>>(Wo, Wb, H_ * H_ / 8);
    gemm256_bt<0, 1><<<256, 512, 0, stream>>>(AO, Wb, out, out, out);
  }
}